// Round 4
// baseline (1258.620 us; speedup 1.0000x reference)
//
#include <hip/hip_runtime.h>
#include <math.h>

#define NNODES 100000
#define NEDGES 3200000
#define NFEAT  512
#define NHID   256
#define NCLASS 40
#define NB_SCAN 98              // ceil(NNODES / 1024)

typedef short  bf16x8 __attribute__((ext_vector_type(8)));
typedef unsigned short u16x8 __attribute__((ext_vector_type(8)));
typedef float  f32x4  __attribute__((ext_vector_type(4)));

__device__ inline unsigned short f2bf_rne(float f) {
    unsigned u = __float_as_uint(f);
    unsigned r = (u + 0x7FFFu + ((u >> 16) & 1u)) >> 16;
    return (unsigned short)r;
}
__device__ inline float bf2f(unsigned short h) {
    return __uint_as_float((unsigned)h << 16);
}

// ============ W1 transpose + hi/lo bf16 split: W1[512][256] -> W1T[256][512]
__global__ __launch_bounds__(256) void w1_split_kernel(
    const float* __restrict__ W1, unsigned short* __restrict__ hi,
    unsigned short* __restrict__ lo)
{
    const int i = blockIdx.x * 256 + threadIdx.x;     // 131072 total
    if (i >= NFEAT * NHID) return;
    const int k = i >> 8;        // row of W1 (K)
    const int n = i & 255;       // col of W1 (N)
    const float f = W1[i];
    const unsigned short h = f2bf_rne(f);
    const unsigned short l = f2bf_rne(f - bf2f(h));
    hi[n * NFEAT + k] = h;
    lo[n * NFEAT + k] = l;
}

// ============ GEMM1 via MFMA: h0 = x @ W1 + b1 ==============================
__global__ __launch_bounds__(256) void gemm1_mfma_kernel(
    const float* __restrict__ x, const unsigned short* __restrict__ Bhi,
    const unsigned short* __restrict__ Blo, const float* __restrict__ b1,
    float* __restrict__ h0)
{
    __shared__ __align__(16) unsigned short As_hi[64 * 40];  // [row][k], pad 40
    __shared__ __align__(16) unsigned short As_lo[64 * 40];
    const int t = threadIdx.x;
    const int lane = t & 63;
    const int w = t >> 6;
    const int row0 = blockIdx.x * 64;
    const int wn0 = w * 64;
    const int fr = lane & 15;        // fragment row/col index
    const int fq = lane >> 4;        // k-group
    const int srow = t >> 2;             // 0..63
    const int skq  = (t & 3) * 8;        // 0,8,16,24
    const int grow = row0 + srow;
    const float* xp = x + (size_t)grow * NFEAT + skq;
    unsigned short* ah = &As_hi[srow * 40 + skq];
    unsigned short* al = &As_lo[srow * 40 + skq];

    f32x4 acc[4][4] = {};

    for (int k0 = 0; k0 < NFEAT; k0 += 32) {
        float v[8];
        if (grow < NNODES) {
            const float4 u0 = *(const float4*)(xp + k0);
            const float4 u1 = *(const float4*)(xp + k0 + 4);
            v[0] = u0.x; v[1] = u0.y; v[2] = u0.z; v[3] = u0.w;
            v[4] = u1.x; v[5] = u1.y; v[6] = u1.z; v[7] = u1.w;
        } else {
            #pragma unroll
            for (int j = 0; j < 8; ++j) v[j] = 0.f;
        }
        u16x8 hv, lv;
        #pragma unroll
        for (int j = 0; j < 8; ++j) {
            const unsigned short h = f2bf_rne(v[j]);
            hv[j] = h;
            lv[j] = f2bf_rne(v[j] - bf2f(h));
        }
        __syncthreads();
        *(u16x8*)ah = hv;
        *(u16x8*)al = lv;
        __syncthreads();

        bf16x8 a_h[4], a_l[4];
        #pragma unroll
        for (int mt = 0; mt < 4; ++mt) {
            const int off = (mt * 16 + fr) * 40 + fq * 8;
            a_h[mt] = *(const bf16x8*)&As_hi[off];
            a_l[mt] = *(const bf16x8*)&As_lo[off];
        }
        bf16x8 b_h[4], b_l[4];
        #pragma unroll
        for (int nt = 0; nt < 4; ++nt) {
            const int n = wn0 + nt * 16 + fr;
            const size_t boff = (size_t)n * NFEAT + k0 + fq * 8;
            b_h[nt] = *(const bf16x8*)(Bhi + boff);
            b_l[nt] = *(const bf16x8*)(Blo + boff);
        }
        #pragma unroll
        for (int mt = 0; mt < 4; ++mt)
            #pragma unroll
            for (int nt = 0; nt < 4; ++nt) {
                acc[mt][nt] = __builtin_amdgcn_mfma_f32_16x16x32_bf16(
                    a_h[mt], b_h[nt], acc[mt][nt], 0, 0, 0);
                acc[mt][nt] = __builtin_amdgcn_mfma_f32_16x16x32_bf16(
                    a_h[mt], b_l[nt], acc[mt][nt], 0, 0, 0);
                acc[mt][nt] = __builtin_amdgcn_mfma_f32_16x16x32_bf16(
                    a_l[mt], b_h[nt], acc[mt][nt], 0, 0, 0);
            }
    }
    #pragma unroll
    for (int mt = 0; mt < 4; ++mt)
        #pragma unroll
        for (int nt = 0; nt < 4; ++nt) {
            const int c = wn0 + nt * 16 + fr;
            const float bias = b1[c];
            const int r0 = row0 + mt * 16 + fq * 4;
            #pragma unroll
            for (int r = 0; r < 4; ++r) {
                const int row = r0 + r;
                if (row < NNODES)
                    h0[(size_t)row * NHID + c] = acc[mt][nt][r] + bias;
            }
        }
}

// ============ GEMM2: h2 = h1 @ W2 + b2  [N,256] x [256,40] ==================
__global__ __launch_bounds__(256) void gemm2_kernel(
    const float* __restrict__ h1, const float* __restrict__ W2,
    const float* __restrict__ b2, float* __restrict__ h2)
{
    __shared__ float Bs[NHID * NCLASS]; // full W2: 40 KB
    __shared__ float As[64][33];
    const int t = threadIdx.x;
    const int row0 = blockIdx.x * 64;
    for (int i = t; i < NHID * NCLASS; i += 256) Bs[i] = W2[i];
    const int r  = t & 63;
    const int cg = (t >> 6) * 10;
    const int am = t >> 2, ak = (t & 3) * 8;
    float acc[10] = {};
    for (int k0 = 0; k0 < NHID; k0 += 32) {
        __syncthreads();
        float4 v0 = make_float4(0.f,0.f,0.f,0.f), v1 = v0;
        const int arow = row0 + am;
        if (arow < NNODES) {
            v0 = *(const float4*)(h1 + (size_t)arow * NHID + k0 + ak);
            v1 = *(const float4*)(h1 + (size_t)arow * NHID + k0 + ak + 4);
        }
        As[am][ak + 0] = v0.x; As[am][ak + 1] = v0.y;
        As[am][ak + 2] = v0.z; As[am][ak + 3] = v0.w;
        As[am][ak + 4] = v1.x; As[am][ak + 5] = v1.y;
        As[am][ak + 6] = v1.z; As[am][ak + 7] = v1.w;
        __syncthreads();
        #pragma unroll
        for (int k = 0; k < 32; ++k) {
            const float a = As[r][k];
            #pragma unroll
            for (int j = 0; j < 10; ++j)
                acc[j] += a * Bs[(k0 + k) * NCLASS + cg + j];
        }
    }
    const int arow = row0 + r;
    if (arow < NNODES) {
        #pragma unroll
        for (int j = 0; j < 10; ++j)
            h2[(size_t)arow * NCLASS + cg + j] = acc[j] + b2[cg + j];
    }
}

// ============ CSR build =====================================================
__global__ __launch_bounds__(256) void zero_int_kernel(int* __restrict__ p, int n)
{
    const int i = blockIdx.x * 256 + threadIdx.x;
    if (i < n) p[i] = 0;
}

// 4 edges per thread: int4 coalesced load, 4 independent fire-and-forget atomics
__global__ __launch_bounds__(256) void hist_kernel(
    const int* __restrict__ ei, int* __restrict__ deg)
{
    const int e = (blockIdx.x * 256 + threadIdx.x) * 4;
    if (e + 3 < NEDGES) {
        const int4 d = *(const int4*)(ei + e);
        atomicAdd(&deg[d.x], 1);
        atomicAdd(&deg[d.y], 1);
        atomicAdd(&deg[d.z], 1);
        atomicAdd(&deg[d.w], 1);
    } else {
        for (int j = e; j < NEDGES; ++j) atomicAdd(&deg[ei[j]], 1);
    }
}

__global__ __launch_bounds__(256) void scan1_kernel(
    const int* __restrict__ deg, int* __restrict__ rowptr, int* __restrict__ bsum)
{
    __shared__ int s[256];
    const int b = blockIdx.x, t = threadIdx.x;
    const int i0 = b * 1024 + t * 4;
    int v[4];
    #pragma unroll
    for (int j = 0; j < 4; ++j) v[j] = (i0 + j < NNODES) ? deg[i0 + j] : 0;
    const int mysum = v[0] + v[1] + v[2] + v[3];
    s[t] = mysum;
    __syncthreads();
    for (int o = 1; o < 256; o <<= 1) {
        const int u = (t >= o) ? s[t - o] : 0;
        __syncthreads();
        s[t] += u;
        __syncthreads();
    }
    int run = s[t] - mysum;
    #pragma unroll
    for (int j = 0; j < 4; ++j) {
        if (i0 + j < NNODES) rowptr[i0 + j] = run;
        run += v[j];
    }
    if (t == 255) bsum[b] = s[255];
}

__global__ __launch_bounds__(128) void scan2_kernel(int* __restrict__ bsum)
{
    __shared__ int s[128];
    const int t = threadIdx.x;
    const int v = (t < NB_SCAN) ? bsum[t] : 0;
    s[t] = v;
    __syncthreads();
    for (int o = 1; o < 128; o <<= 1) {
        const int u = (t >= o) ? s[t - o] : 0;
        __syncthreads();
        s[t] += u;
        __syncthreads();
    }
    if (t < NB_SCAN) bsum[t] = s[t] - v;
}

__global__ __launch_bounds__(256) void scan3_kernel(
    int* __restrict__ rowptr, int* __restrict__ cursor, const int* __restrict__ bsum)
{
    const int b = blockIdx.x, t = threadIdx.x;
    const int i0 = b * 1024 + t * 4;
    const int off = bsum[b];
    #pragma unroll
    for (int j = 0; j < 4; ++j) {
        const int i = i0 + j;
        if (i < NNODES) {
            const int r = rowptr[i] + off;
            rowptr[i] = r;
            cursor[i] = r;
        }
    }
    if (b == 0 && t == 0) rowptr[NNODES] = NEDGES;
}

// 4 edges per thread: int4/float4 loads, 4 independent atomic+store chains
__global__ __launch_bounds__(256) void scatter_kernel(
    const int* __restrict__ ei, const float* __restrict__ ew,
    int* __restrict__ cursor, int2* __restrict__ pairs)
{
    const int e = (blockIdx.x * 256 + threadIdx.x) * 4;
    if (e + 3 < NEDGES) {
        const int4   d = *(const int4*)(ei + e);
        const int4   s = *(const int4*)(ei + NEDGES + e);
        const float4 w = *(const float4*)(ew + e);
        const int p0 = atomicAdd(&cursor[d.x], 1);
        const int p1 = atomicAdd(&cursor[d.y], 1);
        const int p2 = atomicAdd(&cursor[d.z], 1);
        const int p3 = atomicAdd(&cursor[d.w], 1);
        pairs[p0] = make_int2(s.x, __float_as_int(w.x));
        pairs[p1] = make_int2(s.y, __float_as_int(w.y));
        pairs[p2] = make_int2(s.z, __float_as_int(w.z));
        pairs[p3] = make_int2(s.w, __float_as_int(w.w));
    } else {
        for (int j = e; j < NEDGES; ++j) {
            const int dst = ei[j];
            const int p = atomicAdd(&cursor[dst], 1);
            pairs[p] = make_int2(ei[NEDGES + j], __float_as_int(ew[j]));
        }
    }
}

// ============ SpMM1 feature-halved (+fused ReLU): half-wave per dst =========
__global__ __launch_bounds__(256) void spmm1_half_kernel(
    const int* __restrict__ rowptr, const int2* __restrict__ pairs,
    const float* __restrict__ h0, float* __restrict__ h1, int p)
{
    const int dst = blockIdx.x * 8 + (threadIdx.x >> 5);
    const int hl  = threadIdx.x & 31;
    if (dst >= NNODES) return;
    const int beg = rowptr[dst], end = rowptr[dst + 1];
    const float* base = h0 + p * 128 + hl * 4;
    float4 a0 = make_float4(0.f, 0.f, 0.f, 0.f);
    float4 a1 = make_float4(0.f, 0.f, 0.f, 0.f);
    int j = beg;
    for (; j + 1 < end; j += 2) {
        const int2 p0 = pairs[j];
        const int2 p1 = pairs[j + 1];
        const float4 v0 = *(const float4*)(base + (size_t)p0.x * NHID);
        const float4 v1 = *(const float4*)(base + (size_t)p1.x * NHID);
        const float w0 = __int_as_float(p0.y), w1 = __int_as_float(p1.y);
        a0.x = fmaf(v0.x, w0, a0.x); a0.y = fmaf(v0.y, w0, a0.y);
        a0.z = fmaf(v0.z, w0, a0.z); a0.w = fmaf(v0.w, w0, a0.w);
        a1.x = fmaf(v1.x, w1, a1.x); a1.y = fmaf(v1.y, w1, a1.y);
        a1.z = fmaf(v1.z, w1, a1.z); a1.w = fmaf(v1.w, w1, a1.w);
    }
    if (j < end) {
        const int2 p0 = pairs[j];
        const float4 v0 = *(const float4*)(base + (size_t)p0.x * NHID);
        const float w0 = __int_as_float(p0.y);
        a0.x = fmaf(v0.x, w0, a0.x); a0.y = fmaf(v0.y, w0, a0.y);
        a0.z = fmaf(v0.z, w0, a0.z); a0.w = fmaf(v0.w, w0, a0.w);
    }
    float4 o;
    o.x = fmaxf(a0.x + a1.x, 0.f);
    o.y = fmaxf(a0.y + a1.y, 0.f);
    o.z = fmaxf(a0.z + a1.z, 0.f);
    o.w = fmaxf(a0.w + a1.w, 0.f);
    *(float4*)(h1 + (size_t)dst * NHID + p * 128 + hl * 4) = o;
}

// ============ SpMM2 + fused log-softmax: wave per dst =======================
__global__ __launch_bounds__(256) void spmm2_csr_kernel(
    const int* __restrict__ rowptr, const int2* __restrict__ pairs,
    const float* __restrict__ h2, float* __restrict__ out)
{
    const int dst  = blockIdx.x * 4 + (threadIdx.x >> 6);
    const int lane = threadIdx.x & 63;
    if (dst >= NNODES) return;
    const int beg = rowptr[dst], end = rowptr[dst + 1];
    float a0 = 0.f, a1 = 0.f;
    int j = beg;
    for (; j + 1 < end; j += 2) {
        const int2 p0 = pairs[j];
        const int2 p1 = pairs[j + 1];
        float v0 = 0.f, v1 = 0.f;
        if (lane < NCLASS) {
            v0 = h2[(size_t)p0.x * NCLASS + lane];
            v1 = h2[(size_t)p1.x * NCLASS + lane];
        }
        a0 = fmaf(v0, __int_as_float(p0.y), a0);
        a1 = fmaf(v1, __int_as_float(p1.y), a1);
    }
    if (j < end) {
        const int2 p0 = pairs[j];
        float v0 = 0.f;
        if (lane < NCLASS) v0 = h2[(size_t)p0.x * NCLASS + lane];
        a0 = fmaf(v0, __int_as_float(p0.y), a0);
    }
    const float acc = a0 + a1;
    float val = (lane < NCLASS) ? acc : -INFINITY;
    float m = val;
    #pragma unroll
    for (int o = 32; o >= 1; o >>= 1) m = fmaxf(m, __shfl_xor(m, o));
    float ex = (lane < NCLASS) ? expf(val - m) : 0.f;
    float s = ex;
    #pragma unroll
    for (int o = 32; o >= 1; o >>= 1) s += __shfl_xor(s, o);
    if (lane < NCLASS) out[(size_t)dst * NCLASS + lane] = val - m - logf(s);
}

// ============ launch ========================================================
extern "C" void kernel_launch(void* const* d_in, const int* in_sizes, int n_in,
                              void* d_out, int out_size, void* d_ws, size_t ws_size,
                              hipStream_t stream)
{
    const float* x  = (const float*)d_in[0];
    const int*   ei = (const int*)d_in[1];   // [2,E]: dst row then src row
    const float* ew = (const float*)d_in[2];
    const float* W1 = (const float*)d_in[3];
    const float* b1 = (const float*)d_in[4];
    const float* W2 = (const float*)d_in[5];
    const float* b2 = (const float*)d_in[6];
    float* out = (float*)d_out;

    char* ws = (char*)d_ws;
    const size_t H_BYTES = (size_t)NNODES * NHID * 4;        // 102,400,000
    float* h0 = (float*)(ws);
    float* h1 = (float*)(ws + H_BYTES);
    int2* pairs = (int2*)(ws + 2 * H_BYTES);                 // 25,600,000 B
    char* region = ws + 2 * H_BYTES + (size_t)NEDGES * 8;
    // temporal overlap: W1T (hi|lo, 512 KB) lives in region until gemm1 done;
    // rowptr/cursor/bsum (CSR) occupy the same bytes afterwards.
    int* rowptr = (int*)(region);                            // 400,016 B
    int* cursor = (int*)(region + 400032);                   // 400,000 B
    int* bsum   = (int*)(region + 800032);                   // 512 B
    unsigned short* W1T_hi = (unsigned short*)(region);           // 262,144 B
    unsigned short* W1T_lo = (unsigned short*)(region + 262144);  // 262,144 B
    float* h2 = (float*)(ws);          // aliases h0 (dead after spmm1)

    // 1. W1 -> transposed bf16 hi/lo split
    w1_split_kernel<<<(NFEAT * NHID + 255) / 256, 256, 0, stream>>>(W1, W1T_hi, W1T_lo);
    // 2. h0 = x @ W1 + b1  (MFMA, 3-pass hi/lo)
    gemm1_mfma_kernel<<<(NNODES + 63) / 64, 256, 0, stream>>>(x, W1T_hi, W1T_lo, b1, h0);
    // 3. build CSR (cursor/rowptr overwrite W1T — it's dead now)
    zero_int_kernel<<<(NNODES + 255) / 256, 256, 0, stream>>>(cursor, NNODES);
    hist_kernel<<<(NEDGES / 4 + 255) / 256, 256, 0, stream>>>(ei, cursor);
    scan1_kernel<<<NB_SCAN, 256, 0, stream>>>(cursor, rowptr, bsum);
    scan2_kernel<<<1, 128, 0, stream>>>(bsum);
    scan3_kernel<<<NB_SCAN, 256, 0, stream>>>(rowptr, cursor, bsum);
    scatter_kernel<<<(NEDGES / 4 + 255) / 256, 256, 0, stream>>>(ei, ew, cursor, pairs);
    // 4. h1 = relu(spmm(h0)) — two L3-resident feature halves
    spmm1_half_kernel<<<(NNODES + 7) / 8, 256, 0, stream>>>(rowptr, pairs, h0, h1, 0);
    spmm1_half_kernel<<<(NNODES + 7) / 8, 256, 0, stream>>>(rowptr, pairs, h0, h1, 1);
    // 5. h2 = h1 @ W2 + b2
    gemm2_kernel<<<(NNODES + 63) / 64, 256, 0, stream>>>(h1, W2, b2, h2);
    // 6. out = logsoftmax(spmm(h2))
    spmm2_csr_kernel<<<(NNODES + 3) / 4, 256, 0, stream>>>(rowptr, pairs, h2, out);
}

// Round 5
// 972.206 us; speedup vs baseline: 1.2946x; 1.2946x over previous
//
#include <hip/hip_runtime.h>
#include <math.h>

#define NNODES 100000
#define NEDGES 3200000
#define NFEAT  512
#define NHID   256
#define NCLASS 40
#define DPB    128                       // dsts per bucket
#define NBUCK  782                       // ceil(NNODES / DPB)
#define TILE   16384                     // edges per bin block
#define NTILE  196                       // ceil(NEDGES / TILE)

typedef short  bf16x8 __attribute__((ext_vector_type(8)));
typedef unsigned short u16x8 __attribute__((ext_vector_type(8)));
typedef float  f32x4  __attribute__((ext_vector_type(4)));

__device__ inline unsigned short f2bf_rne(float f) {
    unsigned u = __float_as_uint(f);
    unsigned r = (u + 0x7FFFu + ((u >> 16) & 1u)) >> 16;
    return (unsigned short)r;
}
__device__ inline float bf2f(unsigned short h) {
    return __uint_as_float((unsigned)h << 16);
}

// ============ W1 transpose + hi/lo bf16 split ===============================
__global__ __launch_bounds__(256) void w1_split_kernel(
    const float* __restrict__ W1, unsigned short* __restrict__ hi,
    unsigned short* __restrict__ lo)
{
    const int i = blockIdx.x * 256 + threadIdx.x;
    if (i >= NFEAT * NHID) return;
    const int k = i >> 8;
    const int n = i & 255;
    const float f = W1[i];
    const unsigned short h = f2bf_rne(f);
    const unsigned short l = f2bf_rne(f - bf2f(h));
    hi[n * NFEAT + k] = h;
    lo[n * NFEAT + k] = l;
}

// ============ GEMM1 via MFMA: h0 = x @ W1 + b1 ==============================
__global__ __launch_bounds__(256) void gemm1_mfma_kernel(
    const float* __restrict__ x, const unsigned short* __restrict__ Bhi,
    const unsigned short* __restrict__ Blo, const float* __restrict__ b1,
    float* __restrict__ h0)
{
    __shared__ __align__(16) unsigned short As_hi[64 * 40];
    __shared__ __align__(16) unsigned short As_lo[64 * 40];
    const int t = threadIdx.x;
    const int lane = t & 63;
    const int w = t >> 6;
    const int row0 = blockIdx.x * 64;
    const int wn0 = w * 64;
    const int fr = lane & 15;
    const int fq = lane >> 4;
    const int srow = t >> 2;
    const int skq  = (t & 3) * 8;
    const int grow = row0 + srow;
    const float* xp = x + (size_t)grow * NFEAT + skq;
    unsigned short* ah = &As_hi[srow * 40 + skq];
    unsigned short* al = &As_lo[srow * 40 + skq];

    f32x4 acc[4][4] = {};

    for (int k0 = 0; k0 < NFEAT; k0 += 32) {
        float v[8];
        if (grow < NNODES) {
            const float4 u0 = *(const float4*)(xp + k0);
            const float4 u1 = *(const float4*)(xp + k0 + 4);
            v[0] = u0.x; v[1] = u0.y; v[2] = u0.z; v[3] = u0.w;
            v[4] = u1.x; v[5] = u1.y; v[6] = u1.z; v[7] = u1.w;
        } else {
            #pragma unroll
            for (int j = 0; j < 8; ++j) v[j] = 0.f;
        }
        u16x8 hv, lv;
        #pragma unroll
        for (int j = 0; j < 8; ++j) {
            const unsigned short h = f2bf_rne(v[j]);
            hv[j] = h;
            lv[j] = f2bf_rne(v[j] - bf2f(h));
        }
        __syncthreads();
        *(u16x8*)ah = hv;
        *(u16x8*)al = lv;
        __syncthreads();

        bf16x8 a_h[4], a_l[4];
        #pragma unroll
        for (int mt = 0; mt < 4; ++mt) {
            const int off = (mt * 16 + fr) * 40 + fq * 8;
            a_h[mt] = *(const bf16x8*)&As_hi[off];
            a_l[mt] = *(const bf16x8*)&As_lo[off];
        }
        bf16x8 b_h[4], b_l[4];
        #pragma unroll
        for (int nt = 0; nt < 4; ++nt) {
            const int n = wn0 + nt * 16 + fr;
            const size_t boff = (size_t)n * NFEAT + k0 + fq * 8;
            b_h[nt] = *(const bf16x8*)(Bhi + boff);
            b_l[nt] = *(const bf16x8*)(Blo + boff);
        }
        #pragma unroll
        for (int mt = 0; mt < 4; ++mt)
            #pragma unroll
            for (int nt = 0; nt < 4; ++nt) {
                acc[mt][nt] = __builtin_amdgcn_mfma_f32_16x16x32_bf16(
                    a_h[mt], b_h[nt], acc[mt][nt], 0, 0, 0);
                acc[mt][nt] = __builtin_amdgcn_mfma_f32_16x16x32_bf16(
                    a_h[mt], b_l[nt], acc[mt][nt], 0, 0, 0);
                acc[mt][nt] = __builtin_amdgcn_mfma_f32_16x16x32_bf16(
                    a_l[mt], b_h[nt], acc[mt][nt], 0, 0, 0);
            }
    }
    #pragma unroll
    for (int mt = 0; mt < 4; ++mt)
        #pragma unroll
        for (int nt = 0; nt < 4; ++nt) {
            const int c = wn0 + nt * 16 + fr;
            const float bias = b1[c];
            const int r0 = row0 + mt * 16 + fq * 4;
            #pragma unroll
            for (int r = 0; r < 4; ++r) {
                const int row = r0 + r;
                if (row < NNODES)
                    h0[(size_t)row * NHID + c] = acc[mt][nt][r] + bias;
            }
        }
}

// ============ GEMM2: h2 = h1 @ W2 + b2  [N,256] x [256,40] ==================
__global__ __launch_bounds__(256) void gemm2_kernel(
    const float* __restrict__ h1, const float* __restrict__ W2,
    const float* __restrict__ b2, float* __restrict__ h2)
{
    __shared__ float Bs[NHID * NCLASS];
    __shared__ float As[64][33];
    const int t = threadIdx.x;
    const int row0 = blockIdx.x * 64;
    for (int i = t; i < NHID * NCLASS; i += 256) Bs[i] = W2[i];
    const int r  = t & 63;
    const int cg = (t >> 6) * 10;
    const int am = t >> 2, ak = (t & 3) * 8;
    float acc[10] = {};
    for (int k0 = 0; k0 < NHID; k0 += 32) {
        __syncthreads();
        float4 v0 = make_float4(0.f,0.f,0.f,0.f), v1 = v0;
        const int arow = row0 + am;
        if (arow < NNODES) {
            v0 = *(const float4*)(h1 + (size_t)arow * NHID + k0 + ak);
            v1 = *(const float4*)(h1 + (size_t)arow * NHID + k0 + ak + 4);
        }
        As[am][ak + 0] = v0.x; As[am][ak + 1] = v0.y;
        As[am][ak + 2] = v0.z; As[am][ak + 3] = v0.w;
        As[am][ak + 4] = v1.x; As[am][ak + 5] = v1.y;
        As[am][ak + 6] = v1.z; As[am][ak + 7] = v1.w;
        __syncthreads();
        #pragma unroll
        for (int k = 0; k < 32; ++k) {
            const float a = As[r][k];
            #pragma unroll
            for (int j = 0; j < 10; ++j)
                acc[j] += a * Bs[(k0 + k) * NCLASS + cg + j];
        }
    }
    const int arow = row0 + r;
    if (arow < NNODES) {
        #pragma unroll
        for (int j = 0; j < 10; ++j)
            h2[(size_t)arow * NCLASS + cg + j] = acc[j] + b2[cg + j];
    }
}

// ============ CSR build: two-level binned counting sort =====================
// init: zero bucket hist, set rowptr[N]
__global__ __launch_bounds__(256) void csr_init_kernel(
    int* __restrict__ bhist, int* __restrict__ rowptr)
{
    const int i = blockIdx.x * 256 + threadIdx.x;
    if (i < NBUCK) bhist[i] = 0;
    if (i == 0) rowptr[NNODES] = NEDGES;
}

// per-block LDS histogram over buckets, one global atomic per (block,bucket)
__global__ __launch_bounds__(256) void bin_count_kernel(
    const int* __restrict__ ei, int* __restrict__ bhist)
{
    __shared__ int h[NBUCK];
    const int t = threadIdx.x;
    for (int i = t; i < NBUCK; i += 256) h[i] = 0;
    __syncthreads();
    const int base = blockIdx.x * TILE;
    #pragma unroll 1
    for (int it = 0; it < TILE / 1024; ++it) {
        const int e = base + it * 1024 + t * 4;
        if (e + 3 < NEDGES) {
            const int4 d = *(const int4*)(ei + e);
            atomicAdd(&h[d.x >> 7], 1);
            atomicAdd(&h[d.y >> 7], 1);
            atomicAdd(&h[d.z >> 7], 1);
            atomicAdd(&h[d.w >> 7], 1);
        } else {
            for (int j = e; j < NEDGES; ++j) atomicAdd(&h[ei[j] >> 7], 1);
        }
    }
    __syncthreads();
    for (int i = t; i < NBUCK; i += 256)
        if (h[i]) atomicAdd(&bhist[i], h[i]);
}

// single-block exclusive scan of 782 bucket counts -> base & cursor
__global__ __launch_bounds__(1024) void bucket_scan_kernel(
    const int* __restrict__ bhist, int* __restrict__ bbase, int* __restrict__ bcur)
{
    __shared__ int s[1024];
    const int t = threadIdx.x;
    const int v = (t < NBUCK) ? bhist[t] : 0;
    s[t] = v;
    __syncthreads();
    for (int o = 1; o < 1024; o <<= 1) {
        const int u = (t >= o) ? s[t - o] : 0;
        __syncthreads();
        s[t] += u;
        __syncthreads();
    }
    if (t < NBUCK) { bbase[t] = s[t] - v; bcur[t] = s[t] - v; }
    if (t == 1023) bbase[NBUCK] = s[1023];   // == NEDGES
}

// LDS hist -> reserve contiguous ranges -> scatter into bucket-grouped binned[]
// packed: .x = (local_dst << 17) | src   (local<128 -> 7b, src<131072 -> 17b)
__global__ __launch_bounds__(256) void bin_scatter_kernel(
    const int* __restrict__ ei, const float* __restrict__ ew,
    int* __restrict__ bcur, int2* __restrict__ binned)
{
    __shared__ int h[NBUCK];
    __shared__ int cur[NBUCK];
    const int t = threadIdx.x;
    for (int i = t; i < NBUCK; i += 256) h[i] = 0;
    __syncthreads();
    const int base = blockIdx.x * TILE;
    #pragma unroll 1
    for (int it = 0; it < TILE / 1024; ++it) {
        const int e = base + it * 1024 + t * 4;
        if (e + 3 < NEDGES) {
            const int4 d = *(const int4*)(ei + e);
            atomicAdd(&h[d.x >> 7], 1);
            atomicAdd(&h[d.y >> 7], 1);
            atomicAdd(&h[d.z >> 7], 1);
            atomicAdd(&h[d.w >> 7], 1);
        } else {
            for (int j = e; j < NEDGES; ++j) atomicAdd(&h[ei[j] >> 7], 1);
        }
    }
    __syncthreads();
    for (int i = t; i < NBUCK; i += 256)
        if (h[i]) cur[i] = atomicAdd(&bcur[i], h[i]);
    __syncthreads();
    #pragma unroll 1
    for (int it = 0; it < TILE / 1024; ++it) {
        const int e = base + it * 1024 + t * 4;
        if (e + 3 < NEDGES) {
            const int4   d = *(const int4*)(ei + e);
            const int4   s = *(const int4*)(ei + NEDGES + e);
            const float4 w = *(const float4*)(ew + e);
            int p0 = atomicAdd(&cur[d.x >> 7], 1);
            int p1 = atomicAdd(&cur[d.y >> 7], 1);
            int p2 = atomicAdd(&cur[d.z >> 7], 1);
            int p3 = atomicAdd(&cur[d.w >> 7], 1);
            binned[p0] = make_int2(((d.x & 127) << 17) | s.x, __float_as_int(w.x));
            binned[p1] = make_int2(((d.y & 127) << 17) | s.y, __float_as_int(w.y));
            binned[p2] = make_int2(((d.z & 127) << 17) | s.z, __float_as_int(w.z));
            binned[p3] = make_int2(((d.w & 127) << 17) | s.w, __float_as_int(w.w));
        } else {
            for (int j = e; j < NEDGES; ++j) {
                const int dj = ei[j];
                const int p = atomicAdd(&cur[dj >> 7], 1);
                binned[p] = make_int2(((dj & 127) << 17) | ei[NEDGES + j],
                                      __float_as_int(ew[j]));
            }
        }
    }
}

// one block per bucket: local count+scan -> rowptr, then exact dst-order pairs
__global__ __launch_bounds__(256) void regroup_kernel(
    const int* __restrict__ bbase, const int2* __restrict__ binned,
    int* __restrict__ rowptr, int2* __restrict__ pairs)
{
    __shared__ int cnt[DPB];
    __shared__ int s[DPB];
    const int b = blockIdx.x;
    const int t = threadIdx.x;
    const int d0 = b * DPB;
    const int nd = (NNODES - d0 < DPB) ? (NNODES - d0) : DPB;
    if (t < DPB) cnt[t] = 0;
    __syncthreads();
    const int lo = bbase[b], hi = bbase[b + 1];
    for (int idx = lo + t; idx < hi; idx += 256)
        atomicAdd(&cnt[binned[idx].x >> 17], 1);
    __syncthreads();
    const int v = (t < DPB) ? cnt[t] : 0;
    if (t < DPB) s[t] = v;
    __syncthreads();
    for (int o = 1; o < DPB; o <<= 1) {
        const int u = (t >= o && t < DPB) ? s[t - o] : 0;
        __syncthreads();
        if (t < DPB) s[t] += u;
        __syncthreads();
    }
    if (t < nd) {
        const int base = lo + s[t] - v;   // exclusive
        rowptr[d0 + t] = base;
        cnt[t] = base;                    // reuse as cursor
    }
    __syncthreads();
    for (int idx = lo + t; idx < hi; idx += 256) {
        const int2 e = binned[idx];
        const int l = e.x >> 17;
        const int pos = atomicAdd(&cnt[l], 1);
        pairs[pos] = make_int2(e.x & 0x1FFFF, e.y);
    }
}

// ============ SpMM1 feature-halved (+fused ReLU): half-wave per dst =========
__global__ __launch_bounds__(256) void spmm1_half_kernel(
    const int* __restrict__ rowptr, const int2* __restrict__ pairs,
    const float* __restrict__ h0, float* __restrict__ h1, int p)
{
    const int dst = blockIdx.x * 8 + (threadIdx.x >> 5);
    const int hl  = threadIdx.x & 31;
    if (dst >= NNODES) return;
    const int beg = rowptr[dst], end = rowptr[dst + 1];
    const float* base = h0 + p * 128 + hl * 4;
    float4 a0 = make_float4(0.f, 0.f, 0.f, 0.f);
    float4 a1 = make_float4(0.f, 0.f, 0.f, 0.f);
    int j = beg;
    for (; j + 1 < end; j += 2) {
        const int2 p0 = pairs[j];
        const int2 p1 = pairs[j + 1];
        const float4 v0 = *(const float4*)(base + (size_t)p0.x * NHID);
        const float4 v1 = *(const float4*)(base + (size_t)p1.x * NHID);
        const float w0 = __int_as_float(p0.y), w1 = __int_as_float(p1.y);
        a0.x = fmaf(v0.x, w0, a0.x); a0.y = fmaf(v0.y, w0, a0.y);
        a0.z = fmaf(v0.z, w0, a0.z); a0.w = fmaf(v0.w, w0, a0.w);
        a1.x = fmaf(v1.x, w1, a1.x); a1.y = fmaf(v1.y, w1, a1.y);
        a1.z = fmaf(v1.z, w1, a1.z); a1.w = fmaf(v1.w, w1, a1.w);
    }
    if (j < end) {
        const int2 p0 = pairs[j];
        const float4 v0 = *(const float4*)(base + (size_t)p0.x * NHID);
        const float w0 = __int_as_float(p0.y);
        a0.x = fmaf(v0.x, w0, a0.x); a0.y = fmaf(v0.y, w0, a0.y);
        a0.z = fmaf(v0.z, w0, a0.z); a0.w = fmaf(v0.w, w0, a0.w);
    }
    float4 o;
    o.x = fmaxf(a0.x + a1.x, 0.f);
    o.y = fmaxf(a0.y + a1.y, 0.f);
    o.z = fmaxf(a0.z + a1.z, 0.f);
    o.w = fmaxf(a0.w + a1.w, 0.f);
    *(float4*)(h1 + (size_t)dst * NHID + p * 128 + hl * 4) = o;
}

// ============ SpMM2 + fused log-softmax: wave per dst =======================
__global__ __launch_bounds__(256) void spmm2_csr_kernel(
    const int* __restrict__ rowptr, const int2* __restrict__ pairs,
    const float* __restrict__ h2, float* __restrict__ out)
{
    const int dst  = blockIdx.x * 4 + (threadIdx.x >> 6);
    const int lane = threadIdx.x & 63;
    if (dst >= NNODES) return;
    const int beg = rowptr[dst], end = rowptr[dst + 1];
    float a0 = 0.f, a1 = 0.f;
    int j = beg;
    for (; j + 1 < end; j += 2) {
        const int2 p0 = pairs[j];
        const int2 p1 = pairs[j + 1];
        float v0 = 0.f, v1 = 0.f;
        if (lane < NCLASS) {
            v0 = h2[(size_t)p0.x * NCLASS + lane];
            v1 = h2[(size_t)p1.x * NCLASS + lane];
        }
        a0 = fmaf(v0, __int_as_float(p0.y), a0);
        a1 = fmaf(v1, __int_as_float(p1.y), a1);
    }
    if (j < end) {
        const int2 p0 = pairs[j];
        float v0 = 0.f;
        if (lane < NCLASS) v0 = h2[(size_t)p0.x * NCLASS + lane];
        a0 = fmaf(v0, __int_as_float(p0.y), a0);
    }
    const float acc = a0 + a1;
    float val = (lane < NCLASS) ? acc : -INFINITY;
    float m = val;
    #pragma unroll
    for (int o = 32; o >= 1; o >>= 1) m = fmaxf(m, __shfl_xor(m, o));
    float ex = (lane < NCLASS) ? expf(val - m) : 0.f;
    float s = ex;
    #pragma unroll
    for (int o = 32; o >= 1; o >>= 1) s += __shfl_xor(s, o);
    if (lane < NCLASS) out[(size_t)dst * NCLASS + lane] = val - m - logf(s);
}

// ============ launch ========================================================
extern "C" void kernel_launch(void* const* d_in, const int* in_sizes, int n_in,
                              void* d_out, int out_size, void* d_ws, size_t ws_size,
                              hipStream_t stream)
{
    const float* x  = (const float*)d_in[0];
    const int*   ei = (const int*)d_in[1];   // [2,E]: dst row then src row
    const float* ew = (const float*)d_in[2];
    const float* W1 = (const float*)d_in[3];
    const float* b1 = (const float*)d_in[4];
    const float* W2 = (const float*)d_in[5];
    const float* b2 = (const float*)d_in[6];
    float* out = (float*)d_out;

    char* ws = (char*)d_ws;
    const size_t H_BYTES = (size_t)NNODES * NHID * 4;        // 102,400,000
    float* h0 = (float*)(ws);
    float* h1 = (float*)(ws + H_BYTES);
    int2* binned = (int2*)(ws + H_BYTES);    // aliases h1 (dead until spmm1)
    int2* pairs  = (int2*)(ws + 2 * H_BYTES);                // 25,600,000 B
    char* region = ws + 2 * H_BYTES + (size_t)NEDGES * 8;
    // W1T (512 KB) dead after gemm1; CSR arrays occupy the same bytes after.
    unsigned short* W1T_hi = (unsigned short*)(region);           // 262,144 B
    unsigned short* W1T_lo = (unsigned short*)(region + 262144);  // 262,144 B
    int* rowptr = (int*)(region);                            // 400,016 B
    int* bhist  = (int*)(region + 400016);                   // 3,136 B
    int* bbase  = (int*)(region + 403152);                   // 3,136 B (783)
    int* bcur   = (int*)(region + 406288);                   // 3,136 B
    float* h2 = (float*)(ws);          // aliases h0 (dead after spmm1)

    // 1. W1 -> transposed bf16 hi/lo split; h0 = x @ W1 + b1 (MFMA 3-pass)
    w1_split_kernel<<<(NFEAT * NHID + 255) / 256, 256, 0, stream>>>(W1, W1T_hi, W1T_lo);
    gemm1_mfma_kernel<<<(NNODES + 63) / 64, 256, 0, stream>>>(x, W1T_hi, W1T_lo, b1, h0);
    // 2. CSR build: binned counting sort (W1T dead from here)
    csr_init_kernel<<<(NBUCK + 255) / 256, 256, 0, stream>>>(bhist, rowptr);
    bin_count_kernel<<<NTILE, 256, 0, stream>>>(ei, bhist);
    bucket_scan_kernel<<<1, 1024, 0, stream>>>(bhist, bbase, bcur);
    bin_scatter_kernel<<<NTILE, 256, 0, stream>>>(ei, ew, bcur, binned);
    regroup_kernel<<<NBUCK, 256, 0, stream>>>(bbase, binned, rowptr, pairs);
    // 3. h1 = relu(spmm(h0)) — two L3-resident feature halves
    spmm1_half_kernel<<<(NNODES + 7) / 8, 256, 0, stream>>>(rowptr, pairs, h0, h1, 0);
    spmm1_half_kernel<<<(NNODES + 7) / 8, 256, 0, stream>>>(rowptr, pairs, h0, h1, 1);
    // 4. h2 = h1 @ W2 + b2
    gemm2_kernel<<<(NNODES + 63) / 64, 256, 0, stream>>>(h1, W2, b2, h2);
    // 5. out = logsoftmax(spmm(h2))
    spmm2_csr_kernel<<<(NNODES + 3) / 4, 256, 0, stream>>>(rowptr, pairs, h2, out);
}

// Round 6
// 766.810 us; speedup vs baseline: 1.6414x; 1.2679x over previous
//
#include <hip/hip_runtime.h>
#include <hip/hip_fp16.h>
#include <math.h>

#define NNODES 100000
#define NEDGES 3200000
#define NFEAT  512
#define NHID   256
#define NCLASS 40
#define DPB    128                       // dsts per bucket
#define NBUCK  782                       // ceil(NNODES / DPB)
#define TILE   16384                     // edges per bin block
#define NTILE  196                       // ceil(NEDGES / TILE)

typedef short  bf16x8 __attribute__((ext_vector_type(8)));
typedef unsigned short u16x8 __attribute__((ext_vector_type(8)));
typedef float  f32x4  __attribute__((ext_vector_type(4)));
typedef _Float16 half4 __attribute__((ext_vector_type(4)));

__device__ inline unsigned short f2bf_rne(float f) {
    unsigned u = __float_as_uint(f);
    unsigned r = (u + 0x7FFFu + ((u >> 16) & 1u)) >> 16;
    return (unsigned short)r;
}
__device__ inline float bf2f(unsigned short h) {
    return __uint_as_float((unsigned)h << 16);
}

// ============ W1 transpose + hi/lo bf16 split ===============================
__global__ __launch_bounds__(256) void w1_split_kernel(
    const float* __restrict__ W1, unsigned short* __restrict__ hi,
    unsigned short* __restrict__ lo)
{
    const int i = blockIdx.x * 256 + threadIdx.x;
    if (i >= NFEAT * NHID) return;
    const int k = i >> 8;
    const int n = i & 255;
    const float f = W1[i];
    const unsigned short h = f2bf_rne(f);
    const unsigned short l = f2bf_rne(f - bf2f(h));
    hi[n * NFEAT + k] = h;
    lo[n * NFEAT + k] = l;
}

// ============ GEMM1 via MFMA: h0 = fp16(x @ W1 + b1) ========================
__global__ __launch_bounds__(256) void gemm1_mfma_kernel(
    const float* __restrict__ x, const unsigned short* __restrict__ Bhi,
    const unsigned short* __restrict__ Blo, const float* __restrict__ b1,
    _Float16* __restrict__ h0)
{
    __shared__ __align__(16) unsigned short As_hi[64 * 40];
    __shared__ __align__(16) unsigned short As_lo[64 * 40];
    const int t = threadIdx.x;
    const int lane = t & 63;
    const int w = t >> 6;
    const int row0 = blockIdx.x * 64;
    const int wn0 = w * 64;
    const int fr = lane & 15;
    const int fq = lane >> 4;
    const int srow = t >> 2;
    const int skq  = (t & 3) * 8;
    const int grow = row0 + srow;
    const float* xp = x + (size_t)grow * NFEAT + skq;
    unsigned short* ah = &As_hi[srow * 40 + skq];
    unsigned short* al = &As_lo[srow * 40 + skq];

    f32x4 acc[4][4] = {};

    for (int k0 = 0; k0 < NFEAT; k0 += 32) {
        float v[8];
        if (grow < NNODES) {
            const float4 u0 = *(const float4*)(xp + k0);
            const float4 u1 = *(const float4*)(xp + k0 + 4);
            v[0] = u0.x; v[1] = u0.y; v[2] = u0.z; v[3] = u0.w;
            v[4] = u1.x; v[5] = u1.y; v[6] = u1.z; v[7] = u1.w;
        } else {
            #pragma unroll
            for (int j = 0; j < 8; ++j) v[j] = 0.f;
        }
        u16x8 hv, lv;
        #pragma unroll
        for (int j = 0; j < 8; ++j) {
            const unsigned short h = f2bf_rne(v[j]);
            hv[j] = h;
            lv[j] = f2bf_rne(v[j] - bf2f(h));
        }
        __syncthreads();
        *(u16x8*)ah = hv;
        *(u16x8*)al = lv;
        __syncthreads();

        bf16x8 a_h[4], a_l[4];
        #pragma unroll
        for (int mt = 0; mt < 4; ++mt) {
            const int off = (mt * 16 + fr) * 40 + fq * 8;
            a_h[mt] = *(const bf16x8*)&As_hi[off];
            a_l[mt] = *(const bf16x8*)&As_lo[off];
        }
        bf16x8 b_h[4], b_l[4];
        #pragma unroll
        for (int nt = 0; nt < 4; ++nt) {
            const int n = wn0 + nt * 16 + fr;
            const size_t boff = (size_t)n * NFEAT + k0 + fq * 8;
            b_h[nt] = *(const bf16x8*)(Bhi + boff);
            b_l[nt] = *(const bf16x8*)(Blo + boff);
        }
        #pragma unroll
        for (int mt = 0; mt < 4; ++mt)
            #pragma unroll
            for (int nt = 0; nt < 4; ++nt) {
                acc[mt][nt] = __builtin_amdgcn_mfma_f32_16x16x32_bf16(
                    a_h[mt], b_h[nt], acc[mt][nt], 0, 0, 0);
                acc[mt][nt] = __builtin_amdgcn_mfma_f32_16x16x32_bf16(
                    a_h[mt], b_l[nt], acc[mt][nt], 0, 0, 0);
                acc[mt][nt] = __builtin_amdgcn_mfma_f32_16x16x32_bf16(
                    a_l[mt], b_h[nt], acc[mt][nt], 0, 0, 0);
            }
    }
    #pragma unroll
    for (int mt = 0; mt < 4; ++mt)
        #pragma unroll
        for (int nt = 0; nt < 4; ++nt) {
            const int c = wn0 + nt * 16 + fr;
            const float bias = b1[c];
            const int r0 = row0 + mt * 16 + fq * 4;
            #pragma unroll
            for (int r = 0; r < 4; ++r) {
                const int row = r0 + r;
                if (row < NNODES)
                    h0[(size_t)row * NHID + c] = (_Float16)(acc[mt][nt][r] + bias);
            }
        }
}

// ============ GEMM2: h2 = fp16(h1 @ W2 + b2)  [N,256] x [256,40] ============
__global__ __launch_bounds__(256) void gemm2_kernel(
    const float* __restrict__ h1, const float* __restrict__ W2,
    const float* __restrict__ b2, _Float16* __restrict__ h2)
{
    __shared__ float Bs[NHID * NCLASS];
    __shared__ float As[64][33];
    const int t = threadIdx.x;
    const int row0 = blockIdx.x * 64;
    for (int i = t; i < NHID * NCLASS; i += 256) Bs[i] = W2[i];
    const int r  = t & 63;
    const int cg = (t >> 6) * 10;
    const int am = t >> 2, ak = (t & 3) * 8;
    float acc[10] = {};
    for (int k0 = 0; k0 < NHID; k0 += 32) {
        __syncthreads();
        float4 v0 = make_float4(0.f,0.f,0.f,0.f), v1 = v0;
        const int arow = row0 + am;
        if (arow < NNODES) {
            v0 = *(const float4*)(h1 + (size_t)arow * NHID + k0 + ak);
            v1 = *(const float4*)(h1 + (size_t)arow * NHID + k0 + ak + 4);
        }
        As[am][ak + 0] = v0.x; As[am][ak + 1] = v0.y;
        As[am][ak + 2] = v0.z; As[am][ak + 3] = v0.w;
        As[am][ak + 4] = v1.x; As[am][ak + 5] = v1.y;
        As[am][ak + 6] = v1.z; As[am][ak + 7] = v1.w;
        __syncthreads();
        #pragma unroll
        for (int k = 0; k < 32; ++k) {
            const float a = As[r][k];
            #pragma unroll
            for (int j = 0; j < 10; ++j)
                acc[j] += a * Bs[(k0 + k) * NCLASS + cg + j];
        }
    }
    const int arow = row0 + r;
    if (arow < NNODES) {
        #pragma unroll
        for (int j = 0; j < 10; ++j)
            h2[(size_t)arow * NCLASS + cg + j] = (_Float16)(acc[j] + b2[cg + j]);
    }
}

// ============ CSR build: two-level binned counting sort =====================
__global__ __launch_bounds__(256) void csr_init_kernel(
    int* __restrict__ bhist, int* __restrict__ rowptr)
{
    const int i = blockIdx.x * 256 + threadIdx.x;
    if (i < NBUCK) bhist[i] = 0;
    if (i == 0) rowptr[NNODES] = NEDGES;
}

__global__ __launch_bounds__(256) void bin_count_kernel(
    const int* __restrict__ ei, int* __restrict__ bhist)
{
    __shared__ int h[NBUCK];
    const int t = threadIdx.x;
    for (int i = t; i < NBUCK; i += 256) h[i] = 0;
    __syncthreads();
    const int base = blockIdx.x * TILE;
    #pragma unroll 1
    for (int it = 0; it < TILE / 1024; ++it) {
        const int e = base + it * 1024 + t * 4;
        if (e + 3 < NEDGES) {
            const int4 d = *(const int4*)(ei + e);
            atomicAdd(&h[d.x >> 7], 1);
            atomicAdd(&h[d.y >> 7], 1);
            atomicAdd(&h[d.z >> 7], 1);
            atomicAdd(&h[d.w >> 7], 1);
        } else {
            for (int j = e; j < NEDGES; ++j) atomicAdd(&h[ei[j] >> 7], 1);
        }
    }
    __syncthreads();
    for (int i = t; i < NBUCK; i += 256)
        if (h[i]) atomicAdd(&bhist[i], h[i]);
}

__global__ __launch_bounds__(1024) void bucket_scan_kernel(
    const int* __restrict__ bhist, int* __restrict__ bbase, int* __restrict__ bcur)
{
    __shared__ int s[1024];
    const int t = threadIdx.x;
    const int v = (t < NBUCK) ? bhist[t] : 0;
    s[t] = v;
    __syncthreads();
    for (int o = 1; o < 1024; o <<= 1) {
        const int u = (t >= o) ? s[t - o] : 0;
        __syncthreads();
        s[t] += u;
        __syncthreads();
    }
    if (t < NBUCK) { bbase[t] = s[t] - v; bcur[t] = s[t] - v; }
    if (t == 1023) bbase[NBUCK] = s[1023];
}

// packed: .x = (local_dst << 17) | src
__global__ __launch_bounds__(256) void bin_scatter_kernel(
    const int* __restrict__ ei, const float* __restrict__ ew,
    int* __restrict__ bcur, int2* __restrict__ binned)
{
    __shared__ int h[NBUCK];
    __shared__ int cur[NBUCK];
    const int t = threadIdx.x;
    for (int i = t; i < NBUCK; i += 256) h[i] = 0;
    __syncthreads();
    const int base = blockIdx.x * TILE;
    #pragma unroll 1
    for (int it = 0; it < TILE / 1024; ++it) {
        const int e = base + it * 1024 + t * 4;
        if (e + 3 < NEDGES) {
            const int4 d = *(const int4*)(ei + e);
            atomicAdd(&h[d.x >> 7], 1);
            atomicAdd(&h[d.y >> 7], 1);
            atomicAdd(&h[d.z >> 7], 1);
            atomicAdd(&h[d.w >> 7], 1);
        } else {
            for (int j = e; j < NEDGES; ++j) atomicAdd(&h[ei[j] >> 7], 1);
        }
    }
    __syncthreads();
    for (int i = t; i < NBUCK; i += 256)
        if (h[i]) cur[i] = atomicAdd(&bcur[i], h[i]);
    __syncthreads();
    #pragma unroll 1
    for (int it = 0; it < TILE / 1024; ++it) {
        const int e = base + it * 1024 + t * 4;
        if (e + 3 < NEDGES) {
            const int4   d = *(const int4*)(ei + e);
            const int4   s = *(const int4*)(ei + NEDGES + e);
            const float4 w = *(const float4*)(ew + e);
            int p0 = atomicAdd(&cur[d.x >> 7], 1);
            int p1 = atomicAdd(&cur[d.y >> 7], 1);
            int p2 = atomicAdd(&cur[d.z >> 7], 1);
            int p3 = atomicAdd(&cur[d.w >> 7], 1);
            binned[p0] = make_int2(((d.x & 127) << 17) | s.x, __float_as_int(w.x));
            binned[p1] = make_int2(((d.y & 127) << 17) | s.y, __float_as_int(w.y));
            binned[p2] = make_int2(((d.z & 127) << 17) | s.z, __float_as_int(w.z));
            binned[p3] = make_int2(((d.w & 127) << 17) | s.w, __float_as_int(w.w));
        } else {
            for (int j = e; j < NEDGES; ++j) {
                const int dj = ei[j];
                const int p = atomicAdd(&cur[dj >> 7], 1);
                binned[p] = make_int2(((dj & 127) << 17) | ei[NEDGES + j],
                                      __float_as_int(ew[j]));
            }
        }
    }
}

__global__ __launch_bounds__(256) void regroup_kernel(
    const int* __restrict__ bbase, const int2* __restrict__ binned,
    int* __restrict__ rowptr, int2* __restrict__ pairs)
{
    __shared__ int cnt[DPB];
    __shared__ int s[DPB];
    const int b = blockIdx.x;
    const int t = threadIdx.x;
    const int d0 = b * DPB;
    const int nd = (NNODES - d0 < DPB) ? (NNODES - d0) : DPB;
    if (t < DPB) cnt[t] = 0;
    __syncthreads();
    const int lo = bbase[b], hi = bbase[b + 1];
    for (int idx = lo + t; idx < hi; idx += 256)
        atomicAdd(&cnt[binned[idx].x >> 17], 1);
    __syncthreads();
    const int v = (t < DPB) ? cnt[t] : 0;
    if (t < DPB) s[t] = v;
    __syncthreads();
    for (int o = 1; o < DPB; o <<= 1) {
        const int u = (t >= o && t < DPB) ? s[t - o] : 0;
        __syncthreads();
        if (t < DPB) s[t] += u;
        __syncthreads();
    }
    if (t < nd) {
        const int base = lo + s[t] - v;
        rowptr[d0 + t] = base;
        cnt[t] = base;
    }
    __syncthreads();
    for (int idx = lo + t; idx < hi; idx += 256) {
        const int2 e = binned[idx];
        const int l = e.x >> 17;
        const int pos = atomicAdd(&cnt[l], 1);
        pairs[pos] = make_int2(e.x & 0x1FFFF, e.y);
    }
}

// ============ SpMM1 full-row fp16 gather (+fused ReLU): wave per dst ========
__global__ __launch_bounds__(256) void spmm1_f16_kernel(
    const int* __restrict__ rowptr, const int2* __restrict__ pairs,
    const _Float16* __restrict__ h0, float* __restrict__ h1)
{
    const int dst  = blockIdx.x * 4 + (threadIdx.x >> 6);
    const int lane = threadIdx.x & 63;
    if (dst >= NNODES) return;
    const int beg = rowptr[dst], end = rowptr[dst + 1];
    const _Float16* base = h0 + lane * 4;
    float a0[4] = {0.f, 0.f, 0.f, 0.f};
    float a1[4] = {0.f, 0.f, 0.f, 0.f};
    int j = beg;
    for (; j + 1 < end; j += 2) {
        const int2 p0 = pairs[j];
        const int2 p1 = pairs[j + 1];
        const half4 v0 = *(const half4*)(base + (size_t)p0.x * NHID);
        const half4 v1 = *(const half4*)(base + (size_t)p1.x * NHID);
        const float w0 = __int_as_float(p0.y), w1 = __int_as_float(p1.y);
        #pragma unroll
        for (int k = 0; k < 4; ++k) {
            a0[k] = fmaf((float)v0[k], w0, a0[k]);
            a1[k] = fmaf((float)v1[k], w1, a1[k]);
        }
    }
    if (j < end) {
        const int2 p0 = pairs[j];
        const half4 v0 = *(const half4*)(base + (size_t)p0.x * NHID);
        const float w0 = __int_as_float(p0.y);
        #pragma unroll
        for (int k = 0; k < 4; ++k)
            a0[k] = fmaf((float)v0[k], w0, a0[k]);
    }
    float4 o;
    o.x = fmaxf(a0[0] + a1[0], 0.f);
    o.y = fmaxf(a0[1] + a1[1], 0.f);
    o.z = fmaxf(a0[2] + a1[2], 0.f);
    o.w = fmaxf(a0[3] + a1[3], 0.f);
    *(float4*)(h1 + (size_t)dst * NHID + lane * 4) = o;
}

// ============ SpMM2 (fp16 gather) + fused log-softmax: wave per dst =========
__global__ __launch_bounds__(256) void spmm2_csr_kernel(
    const int* __restrict__ rowptr, const int2* __restrict__ pairs,
    const _Float16* __restrict__ h2, float* __restrict__ out)
{
    const int dst  = blockIdx.x * 4 + (threadIdx.x >> 6);
    const int lane = threadIdx.x & 63;
    if (dst >= NNODES) return;
    const int beg = rowptr[dst], end = rowptr[dst + 1];
    float a0 = 0.f, a1 = 0.f;
    int j = beg;
    for (; j + 1 < end; j += 2) {
        const int2 p0 = pairs[j];
        const int2 p1 = pairs[j + 1];
        float v0 = 0.f, v1 = 0.f;
        if (lane < NCLASS) {
            v0 = (float)h2[(size_t)p0.x * NCLASS + lane];
            v1 = (float)h2[(size_t)p1.x * NCLASS + lane];
        }
        a0 = fmaf(v0, __int_as_float(p0.y), a0);
        a1 = fmaf(v1, __int_as_float(p1.y), a1);
    }
    if (j < end) {
        const int2 p0 = pairs[j];
        float v0 = 0.f;
        if (lane < NCLASS) v0 = (float)h2[(size_t)p0.x * NCLASS + lane];
        a0 = fmaf(v0, __int_as_float(p0.y), a0);
    }
    const float acc = a0 + a1;
    float val = (lane < NCLASS) ? acc : -INFINITY;
    float m = val;
    #pragma unroll
    for (int o = 32; o >= 1; o >>= 1) m = fmaxf(m, __shfl_xor(m, o));
    float ex = (lane < NCLASS) ? expf(val - m) : 0.f;
    float s = ex;
    #pragma unroll
    for (int o = 32; o >= 1; o >>= 1) s += __shfl_xor(s, o);
    if (lane < NCLASS) out[(size_t)dst * NCLASS + lane] = val - m - logf(s);
}

// ============ launch ========================================================
extern "C" void kernel_launch(void* const* d_in, const int* in_sizes, int n_in,
                              void* d_out, int out_size, void* d_ws, size_t ws_size,
                              hipStream_t stream)
{
    const float* x  = (const float*)d_in[0];
    const int*   ei = (const int*)d_in[1];   // [2,E]: dst row then src row
    const float* ew = (const float*)d_in[2];
    const float* W1 = (const float*)d_in[3];
    const float* b1 = (const float*)d_in[4];
    const float* W2 = (const float*)d_in[5];
    const float* b2 = (const float*)d_in[6];
    float* out = (float*)d_out;

    char* ws = (char*)d_ws;
    const size_t H_BYTES = (size_t)NNODES * NHID * 4;        // 102,400,000
    _Float16* h0 = (_Float16*)(ws);          // 51.2 MB (fp16), in h0 region
    float* h1 = (float*)(ws + H_BYTES);      // 102.4 MB fp32
    int2* binned = (int2*)(ws + H_BYTES);    // aliases h1 (dead until spmm1)
    int2* pairs  = (int2*)(ws + 2 * H_BYTES);                // 25,600,000 B
    char* region = ws + 2 * H_BYTES + (size_t)NEDGES * 8;
    // W1T (512 KB) dead after gemm1; CSR arrays occupy the same bytes after.
    unsigned short* W1T_hi = (unsigned short*)(region);           // 262,144 B
    unsigned short* W1T_lo = (unsigned short*)(region + 262144);  // 262,144 B
    int* rowptr = (int*)(region);                            // 400,016 B
    int* bhist  = (int*)(region + 400016);                   // 3,136 B
    int* bbase  = (int*)(region + 403152);                   // 3,136 B (783)
    int* bcur   = (int*)(region + 406288);                   // 3,136 B
    _Float16* h2 = (_Float16*)(ws);    // 8 MB fp16, aliases h0 (dead after spmm1)

    // 1. W1 -> transposed bf16 hi/lo split; h0 = fp16(x @ W1 + b1)
    w1_split_kernel<<<(NFEAT * NHID + 255) / 256, 256, 0, stream>>>(W1, W1T_hi, W1T_lo);
    gemm1_mfma_kernel<<<(NNODES + 63) / 64, 256, 0, stream>>>(x, W1T_hi, W1T_lo, b1, h0);
    // 2. CSR build: binned counting sort (W1T dead from here)
    csr_init_kernel<<<(NBUCK + 255) / 256, 256, 0, stream>>>(bhist, rowptr);
    bin_count_kernel<<<NTILE, 256, 0, stream>>>(ei, bhist);
    bucket_scan_kernel<<<1, 1024, 0, stream>>>(bhist, bbase, bcur);
    bin_scatter_kernel<<<NTILE, 256, 0, stream>>>(ei, ew, bcur, binned);
    regroup_kernel<<<NBUCK, 256, 0, stream>>>(bbase, binned, rowptr, pairs);
    // 3. h1 = relu(spmm(h0)) — single full-row fp16-gather pass
    spmm1_f16_kernel<<<(NNODES + 3) / 4, 256, 0, stream>>>(rowptr, pairs, h0, h1);
    // 4. h2 = fp16(h1 @ W2 + b2)
    gemm2_kernel<<<(NNODES + 63) / 64, 256, 0, stream>>>(h1, W2, b2, h2);
    // 5. out = logsoftmax(spmm(h2)) — fp16 gather
    spmm2_csr_kernel<<<(NNODES + 3) / 4, 256, 0, stream>>>(rowptr, pairs, h2, out);
}